// Round 1
// baseline (1884.502 us; speedup 1.0000x reference)
//
#include <hip/hip_runtime.h>

typedef __attribute__((ext_vector_type(8))) short bf16x8;
typedef __attribute__((ext_vector_type(4))) float f32x4;
typedef __attribute__((ext_vector_type(8))) unsigned short u16x8;

__device__ __forceinline__ float bf2f(short s) {
  unsigned u = ((unsigned)(unsigned short)s) << 16;
  return __builtin_bit_cast(float, u);
}
__device__ __forceinline__ unsigned short f2bf(float f) {
  unsigned u = __builtin_bit_cast(unsigned, f);
  u = (u + 0x7fffu + ((u >> 16) & 1u)) >> 16;
  return (unsigned short)u;
}

// ---------------- convert f32 -> bf16 (no transpose) ----------------
__global__ __launch_bounds__(256)
void cvt_f32_bf16(const float* __restrict__ src, unsigned short* __restrict__ dst, long n) {
  long i = ((long)blockIdx.x * 256 + threadIdx.x) * 8;
  if (i + 8 > n) return;
  float4 a = *(const float4*)(src + i);
  float4 b = *(const float4*)(src + i + 4);
  u16x8 o;
  o[0] = f2bf(a.x); o[1] = f2bf(a.y); o[2] = f2bf(a.z); o[3] = f2bf(a.w);
  o[4] = f2bf(b.x); o[5] = f2bf(b.y); o[6] = f2bf(b.z); o[7] = f2bf(b.w);
  *(u16x8*)(dst + i) = o;
}

// ---------------- transpose f32[R,C] -> bf16[C,R] ----------------
__global__ __launch_bounds__(256)
void transpose_f32_bf16(const float* __restrict__ src, unsigned short* __restrict__ dst,
                        int R, int C, long sb, long db) {
  __shared__ float tile[32][33];
  src += (long)blockIdx.z * sb;
  dst += (long)blockIdx.z * db;
  int bx = blockIdx.x * 32, by = blockIdx.y * 32;
  int tx = threadIdx.x, ty = threadIdx.y;
  #pragma unroll
  for (int i = ty; i < 32; i += 8)
    tile[i][tx] = src[(long)(by + i) * C + bx + tx];
  __syncthreads();
  #pragma unroll
  for (int i = ty; i < 32; i += 8)
    dst[(long)(bx + i) * R + by + tx] = f2bf(tile[tx][i]);
}

// ---------------- bf16 MFMA GEMM: C[M,N] = A[M,K] @ Bt[N,K]^T ----------------
// 128x128 tile, BK=64, 4 waves (2x2), each wave 64x64 via 4x4 frags of 16x16x32.
template<bool HAS_BIAS, bool RELU>
__global__ __launch_bounds__(256, 2)
void gemm_bf16(const unsigned short* __restrict__ A,
               const unsigned short* __restrict__ Bt,
               const float* __restrict__ bias,
               unsigned short* __restrict__ C,
               int M, int N, int K, long sA, long sB, long sBias, long sC) {
  (void)M;
  __shared__ unsigned short As[128 * 64];
  __shared__ unsigned short Bs[128 * 64];
  const int t = threadIdx.x;
  const int lane = t & 63;
  const int w = t >> 6, wr = w >> 1, wc = w & 1;
  const int m0 = blockIdx.y * 128, n0 = blockIdx.x * 128;
  const int z = blockIdx.z;
  A += (long)z * sA;
  Bt += (long)z * sB;
  C += (long)z * sC;
  const int srow = t >> 3, schunk = t & 7;  // 32 rows/pass, 8x16B chunks per 128B row

  f32x4 acc[4][4] = {};

  for (int kt = 0; kt < K; kt += 64) {
    float4 ra[4], rb[4];
    #pragma unroll
    for (int rr = 0; rr < 4; ++rr) {
      const int row = srow + rr * 32;
      ra[rr] = *(const float4*)(A + (long)(m0 + row) * K + kt + schunk * 8);
      rb[rr] = *(const float4*)(Bt + (long)(n0 + row) * K + kt + schunk * 8);
    }
    __syncthreads();  // prior compute done reading LDS
    #pragma unroll
    for (int rr = 0; rr < 4; ++rr) {
      const int row = srow + rr * 32;
      const int byte = row * 128 + ((schunk * 16) ^ ((row & 7) << 4));
      *(float4*)((char*)As + byte) = ra[rr];
      *(float4*)((char*)Bs + byte) = rb[rr];
    }
    __syncthreads();
    #pragma unroll
    for (int ks = 0; ks < 2; ++ks) {
      bf16x8 af[4], bfr[4];
      #pragma unroll
      for (int mi = 0; mi < 4; ++mi) {
        const int row = wr * 64 + mi * 16 + (lane & 15);
        const int byte = row * 128 + (((ks * 64) + ((lane >> 4) * 16)) ^ ((row & 7) << 4));
        af[mi] = *(const bf16x8*)((const char*)As + byte);
      }
      #pragma unroll
      for (int ni = 0; ni < 4; ++ni) {
        const int row = wc * 64 + ni * 16 + (lane & 15);
        const int byte = row * 128 + (((ks * 64) + ((lane >> 4) * 16)) ^ ((row & 7) << 4));
        bfr[ni] = *(const bf16x8*)((const char*)Bs + byte);
      }
      #pragma unroll
      for (int mi = 0; mi < 4; ++mi)
        #pragma unroll
        for (int ni = 0; ni < 4; ++ni)
          acc[mi][ni] = __builtin_amdgcn_mfma_f32_16x16x32_bf16(af[mi], bfr[ni], acc[mi][ni], 0, 0, 0);
    }
  }

  #pragma unroll
  for (int mi = 0; mi < 4; ++mi) {
    #pragma unroll
    for (int ni = 0; ni < 4; ++ni) {
      const int colg = n0 + wc * 64 + ni * 16 + (lane & 15);
      float bv = 0.f;
      if (HAS_BIAS) bv = bias[(long)z * sBias + colg];
      #pragma unroll
      for (int r = 0; r < 4; ++r) {
        const int rowg = m0 + wr * 64 + mi * 16 + (lane >> 4) * 4 + r;
        float v = acc[mi][ni][r] + bv;
        if (RELU) v = fmaxf(v, 0.f);
        C[(long)rowg * N + colg] = f2bf(v);
      }
    }
  }
}

// ---------------- pairwise reduce: on[p,b] ----------------
// Block per b. Stage U,V (8x4096 bf16 = 64KB, k-XOR-swizzled) in LDS.
// Thread t: pair p = t&63 (56 used), h-quarter q = t>>6.
__global__ __launch_bounds__(256)
void pair_reduce_kernel(const unsigned short* __restrict__ UVT,
                        const float* __restrict__ bon1, const float* __restrict__ Won2,
                        const float* __restrict__ bon2,
                        float* __restrict__ out, int Mc) {
  __shared__ unsigned short uv[8 * 4096];
  const int b = blockIdx.x, t = threadIdx.x;
  const long kstride = (long)Mc * 6144;
  const unsigned short* src = UVT + (long)b * 6144;
  for (int k = 0; k < 8; ++k) {
    const unsigned short* s = src + (long)k * kstride;
    #pragma unroll
    for (int c0 = 0; c0 < 2; ++c0) {
      int c = c0 * 256 + t;
      int byte = k * 8192 + ((c * 16) ^ ((k & 7) << 4));
      *(float4*)((char*)uv + byte) = *(const float4*)(s + c * 8);
    }
  }
  __syncthreads();
  const int p = t & 63, q = t >> 6;
  float acc = 0.f;
  if (p < 56) {
    const int i = p / 7;
    const int jj = p % 7;
    const int j = jj + (jj >= i);
    const char* ubase = (const char*)uv + i * 8192;
    const char* vbase = (const char*)uv + j * 8192;
    const int uswz = (i & 7) << 4, vswz = (j & 7) << 4;
    for (int it = 0; it < 64; ++it) {
      const int h = q * 512 + it * 8;
      bf16x8 uu = *(const bf16x8*)(ubase + ((h * 2) ^ uswz));
      bf16x8 vv = *(const bf16x8*)(vbase + ((4096 + h * 2) ^ vswz));
      float4 ba = *(const float4*)(bon1 + h);
      float4 bb = *(const float4*)(bon1 + h + 4);
      float4 wa = *(const float4*)(Won2 + h);
      float4 wb = *(const float4*)(Won2 + h + 4);
      float bs[8] = {ba.x, ba.y, ba.z, ba.w, bb.x, bb.y, bb.z, bb.w};
      float wv[8] = {wa.x, wa.y, wa.z, wa.w, wb.x, wb.y, wb.z, wb.w};
      #pragma unroll
      for (int e = 0; e < 8; ++e) {
        float x = bf2f(uu[e]) + bf2f(vv[e]) + bs[e];
        acc += fmaxf(x, 0.f) * wv[e];
      }
    }
  }
  __syncthreads();
  float* red = (float*)uv;  // reuse LDS after all reads done
  red[q * 64 + p] = acc;
  __syncthreads();
  if (t < 56)
    out[(long)b * 64 + t] = red[t] + red[64 + t] + red[128 + t] + red[192 + t] + bon2[0];
}

// ---------------- clear heads: clear[k,b] ----------------
__global__ __launch_bounds__(256)
void clear_kernel(const unsigned short* __restrict__ UVT,
                  const float* __restrict__ bc1, const float* __restrict__ Wc2,
                  const float* __restrict__ bc2, float* __restrict__ out, int Mc) {
  int b = blockIdx.x, k = blockIdx.y, t = threadIdx.x;
  const unsigned short* Tsrc = UVT + ((long)k * Mc + b) * 6144 + 4096;
  int h = t * 8;
  bf16x8 tt = *(const bf16x8*)(Tsrc + h);
  float acc = 0.f;
  #pragma unroll
  for (int e = 0; e < 8; ++e) {
    float x = bf2f(tt[e]) + bc1[h + e];
    acc += fmaxf(x, 0.f) * Wc2[h + e];
  }
  #pragma unroll
  for (int off = 32; off > 0; off >>= 1)
    acc += __shfl_down(acc, off, 64);
  __shared__ float ws4[4];
  int lane = t & 63, wv = t >> 6;
  if (lane == 0) ws4[wv] = acc;
  __syncthreads();
  if (t == 0)
    out[(long)b * 64 + 56 + k] = ws4[0] + ws4[1] + ws4[2] + ws4[3] + bc2[0];
}

extern "C" void kernel_launch(void* const* d_in, const int* in_sizes, int n_in,
                              void* d_out, int out_size, void* d_ws, size_t ws_size,
                              hipStream_t stream) {
  (void)in_sizes; (void)n_in; (void)out_size;
  const float* input = (const float*)d_in[0];
  const float* b1    = (const float*)d_in[2];
  const float* W1    = (const float*)d_in[1];
  const float* W2    = (const float*)d_in[3];
  const float* b2    = (const float*)d_in[4];
  const float* Won1  = (const float*)d_in[5];
  const float* bon1  = (const float*)d_in[6];
  const float* Won2  = (const float*)d_in[7];
  const float* bon2  = (const float*)d_in[8];
  const float* Wc1   = (const float*)d_in[9];
  const float* bc1   = (const float*)d_in[10];
  const float* Wc2   = (const float*)d_in[11];
  const float* bc2   = (const float*)d_in[12];
  float* out = (float*)d_out;

  char* base = (char*)d_ws;
  unsigned short* inputb = (unsigned short*)(base);                 //  8 MB
  unsigned short* W1T    = (unsigned short*)(base + 8388608L);      // 32 MB
  unsigned short* W2T    = (unsigned short*)(base + 41943040L);     //  8 MB
  unsigned short* WcatT  = (unsigned short*)(base + 50331648L);     //  3 MB
  char* chunkbase = base + 53477376L;

  // pick fewest chunks that fit ws: per-chunk = Mc * 135168 bytes
  int nc = 32;
  const int opts[6] = {1, 2, 4, 8, 16, 32};
  for (int oi = 0; oi < 6; ++oi) {
    long Mc_ = 4096 / opts[oi];
    if (53477376L + Mc_ * 135168L <= (long)ws_size) { nc = opts[oi]; break; }
  }
  const int Mc = 4096 / nc;
  unsigned short* hbuf   = (unsigned short*)chunkbase;
  unsigned short* embbuf = (unsigned short*)(chunkbase + (long)Mc * 32768L);
  unsigned short* UVTbuf = (unsigned short*)(chunkbase + (long)Mc * 32768L + (long)Mc * 4096L);

  dim3 tb(32, 8);
  // input -> bf16
  cvt_f32_bf16<<<dim3(2048), 256, 0, stream>>>(input, inputb, (long)4096 * 1024);
  // W1[k] [1024,2048] -> W1T[k] [2048,1024]
  transpose_f32_bf16<<<dim3(64, 32, 8), tb, 0, stream>>>(W1, W1T, 1024, 2048,
                                                         (long)1024 * 2048, (long)2048 * 1024);
  // W2[k] [2048,256] -> W2T[k] [256,2048]
  transpose_f32_bf16<<<dim3(8, 64, 8), tb, 0, stream>>>(W2, W2T, 2048, 256,
                                                        (long)2048 * 256, (long)256 * 2048);
  // WcatT [6144,256]: rows 0..2047 = Won1[0:256,:]^T, 2048..4095 = Won1[256:512,:]^T, 4096..6143 = Wc1^T
  transpose_f32_bf16<<<dim3(64, 8, 1), tb, 0, stream>>>(Won1, WcatT, 256, 2048, 0, 0);
  transpose_f32_bf16<<<dim3(64, 8, 1), tb, 0, stream>>>(Won1 + 256 * 2048, WcatT + (long)2048 * 256, 256, 2048, 0, 0);
  transpose_f32_bf16<<<dim3(64, 8, 1), tb, 0, stream>>>(Wc1, WcatT + (long)4096 * 256, 256, 2048, 0, 0);

  for (int cc = 0; cc < nc; ++cc) {
    const long b0 = (long)cc * Mc;
    // h[k] = relu(input @ W1[k] + b1[k])   [Mc,2048]
    gemm_bf16<true, true><<<dim3(16, Mc / 128, 8), 256, 0, stream>>>(
        inputb + b0 * 1024, W1T, b1, hbuf, Mc, 2048, 1024,
        0L, (long)2048 * 1024, 2048L, (long)Mc * 2048);
    // emb[k] = h[k] @ W2[k] + b2[k]        [Mc,256]
    gemm_bf16<true, false><<<dim3(2, Mc / 128, 8), 256, 0, stream>>>(
        hbuf, W2T, b2, embbuf, Mc, 256, 2048,
        (long)Mc * 2048, (long)256 * 2048, 256L, (long)Mc * 256);
    // UVT[k] = emb[k] @ [Won1_top | Won1_bot | Wc1]   [Mc,6144]
    gemm_bf16<false, false><<<dim3(48, Mc / 128, 8), 256, 0, stream>>>(
        embbuf, WcatT, nullptr, UVTbuf, Mc, 6144, 256,
        (long)Mc * 256, 0L, 0L, (long)Mc * 6144);
    // on[p,b] and clear[k,b]
    pair_reduce_kernel<<<dim3(Mc), 256, 0, stream>>>(UVTbuf, bon1, Won2, bon2, out + b0 * 64, Mc);
    clear_kernel<<<dim3(Mc, 8), 256, 0, stream>>>(UVTbuf, bc1, Wc2, bc2, out + b0 * 64, Mc);
  }
}

// Round 2
// 713.882 us; speedup vs baseline: 2.6398x; 2.6398x over previous
//
#include <hip/hip_runtime.h>

typedef __attribute__((ext_vector_type(8))) short bf16x8;
typedef __attribute__((ext_vector_type(4))) float f32x4;
typedef __attribute__((ext_vector_type(8))) unsigned short u16x8;

__device__ __forceinline__ float bf2f(short s) {
  unsigned u = ((unsigned)(unsigned short)s) << 16;
  return __builtin_bit_cast(float, u);
}
__device__ __forceinline__ unsigned short f2bf(float f) {
  unsigned u = __builtin_bit_cast(unsigned, f);
  u = (u + 0x7fffu + ((u >> 16) & 1u)) >> 16;
  return (unsigned short)u;
}
__device__ __forceinline__ void gload16(const unsigned short* g, unsigned short* l) {
  __builtin_amdgcn_global_load_lds(
      (const __attribute__((address_space(1))) void*)g,
      (__attribute__((address_space(3))) void*)l, 16, 0, 0);
}

// ---------------- convert f32 -> bf16 ----------------
__global__ __launch_bounds__(256)
void cvt_f32_bf16(const float* __restrict__ src, unsigned short* __restrict__ dst, long n) {
  long i = ((long)blockIdx.x * 256 + threadIdx.x) * 8;
  if (i + 8 > n) return;
  float4 a = *(const float4*)(src + i);
  float4 b = *(const float4*)(src + i + 4);
  u16x8 o;
  o[0] = f2bf(a.x); o[1] = f2bf(a.y); o[2] = f2bf(a.z); o[3] = f2bf(a.w);
  o[4] = f2bf(b.x); o[5] = f2bf(b.y); o[6] = f2bf(b.z); o[7] = f2bf(b.w);
  *(u16x8*)(dst + i) = o;
}

// ---------------- transpose f32[R,C] -> bf16[C,R] ----------------
__global__ __launch_bounds__(256)
void transpose_f32_bf16(const float* __restrict__ src, unsigned short* __restrict__ dst,
                        int R, int C, long sb, long db) {
  __shared__ float tile[32][33];
  src += (long)blockIdx.z * sb;
  dst += (long)blockIdx.z * db;
  int bx = blockIdx.x * 32, by = blockIdx.y * 32;
  int tx = threadIdx.x, ty = threadIdx.y;
  #pragma unroll
  for (int i = ty; i < 32; i += 8)
    tile[i][tx] = src[(long)(by + i) * C + bx + tx];
  __syncthreads();
  #pragma unroll
  for (int i = ty; i < 32; i += 8)
    dst[(long)(bx + i) * R + by + tx] = f2bf(tile[tx][i]);
}

// ---------------- bf16 MFMA GEMM: C[M,N] = A[M,K] @ Bt[N,K]^T ----------------
// m97 structure: 128x128 tile, BK=64, 4 waves (2x2), global_load_lds staging,
// linear LDS, 2-barrier loop. 1D grid with bijective XCD-chunked swizzle.
template<bool HAS_BIAS, bool RELU>
__global__ __launch_bounds__(256, 2)
void gemm_bf16(const unsigned short* __restrict__ A,
               const unsigned short* __restrict__ Bt,
               const float* __restrict__ bias,
               unsigned short* __restrict__ C,
               int N, int K, int nx, int ny,
               long sA, long sB, long sBias, long sC) {
  __shared__ unsigned short As[128 * 64];
  __shared__ unsigned short Bs[128 * 64];
  const int t = threadIdx.x;
  const int lane = t & 63;
  const int w = t >> 6, wr = w >> 1, wc = w & 1;

  // XCD-chunked swizzle (nwg always a multiple of 8 here -> bijective)
  const int nwg = gridDim.x;
  const int cpx = nwg >> 3;
  const int id = blockIdx.x;
  const int sw = (id & 7) * cpx + (id >> 3);
  const int x = sw % nx;
  const int yz = sw / nx;
  const int y = yz % ny;
  const int z = yz / ny;
  const int m0 = y * 128, n0 = x * 128;

  A += (long)z * sA;
  Bt += (long)z * sB;
  C += (long)z * sC;

  const int po = w * 4;             // this wave's first 1KB pass
  const int prow = lane >> 3;       // row within 8-row pass group
  const int pcol = (lane & 7) * 8;  // element col within 64

  f32x4 acc[4][4] = {};

  for (int kt = 0; kt < K; kt += 64) {
    __syncthreads();  // all waves done reading previous tile
    #pragma unroll
    for (int p = 0; p < 4; ++p) {
      const int q = po + p;
      const int row = q * 8 + prow;
      gload16(A + (long)(m0 + row) * K + kt + pcol, As + q * 512);
      gload16(Bt + (long)(n0 + row) * K + kt + pcol, Bs + q * 512);
    }
    __syncthreads();  // drains vmcnt -> tile resident
    #pragma unroll
    for (int ks = 0; ks < 2; ++ks) {
      bf16x8 af[4], bfr[4];
      #pragma unroll
      for (int mi = 0; mi < 4; ++mi) {
        const int row = wr * 64 + mi * 16 + (lane & 15);
        af[mi] = *(const bf16x8*)((const char*)As + row * 128 + ks * 64 + (lane >> 4) * 16);
      }
      #pragma unroll
      for (int ni = 0; ni < 4; ++ni) {
        const int row = wc * 64 + ni * 16 + (lane & 15);
        bfr[ni] = *(const bf16x8*)((const char*)Bs + row * 128 + ks * 64 + (lane >> 4) * 16);
      }
      #pragma unroll
      for (int mi = 0; mi < 4; ++mi)
        #pragma unroll
        for (int ni = 0; ni < 4; ++ni)
          acc[mi][ni] = __builtin_amdgcn_mfma_f32_16x16x32_bf16(af[mi], bfr[ni], acc[mi][ni], 0, 0, 0);
    }
  }

  #pragma unroll
  for (int mi = 0; mi < 4; ++mi) {
    #pragma unroll
    for (int ni = 0; ni < 4; ++ni) {
      const int colg = n0 + wc * 64 + ni * 16 + (lane & 15);
      float bv = 0.f;
      if (HAS_BIAS) bv = bias[(long)z * sBias + colg];
      #pragma unroll
      for (int r = 0; r < 4; ++r) {
        const int rowg = m0 + wr * 64 + mi * 16 + (lane >> 4) * 4 + r;
        float v = acc[mi][ni][r] + bv;
        if (RELU) v = fmaxf(v, 0.f);
        C[(long)rowg * N + colg] = f2bf(v);
      }
    }
  }
}

// ---------------- fused clear heads: clear[k,b] = Wc2 . relu(emb @ Wc1 + bc1) ----------------
// Block (b-tile of 128, k). emb tile resident in LDS (swizzled); Wc1T streamed
// via global_load_lds; per-row dot with Wc2 accumulated in registers.
__global__ __launch_bounds__(256, 2)
void clear_fused(const unsigned short* __restrict__ emb,   // [8][Mc][256]
                 const unsigned short* __restrict__ Wc1T,  // [2048][256]
                 const float* __restrict__ bc1, const float* __restrict__ Wc2,
                 const float* __restrict__ bc2,
                 float* __restrict__ out, int Mc) {
  __shared__ unsigned short Ae[128 * 256];  // 64KB, XOR-swizzled rows of 512B
  __shared__ unsigned short Bs[128 * 64];   // 16KB linear
  __shared__ float red[2][128];
  const int t = threadIdx.x;
  const int lane = t & 63;
  const int w = t >> 6, wr = w >> 1, wc = w & 1;
  const int k = blockIdx.y;
  const int m0 = blockIdx.x * 128;
  const unsigned short* A = emb + ((long)k * Mc + m0) * 256;

  // stage emb tile once (reg path, swizzled to kill 16-way conflicts on A reads)
  {
    const int srow = t >> 5;
    const int sc = t & 31;
    #pragma unroll
    for (int pass = 0; pass < 16; ++pass) {
      const int row = pass * 8 + srow;
      float4 v = *(const float4*)(A + (long)row * 256 + sc * 8);
      *(float4*)((char*)Ae + row * 512 + ((sc * 16) ^ ((row & 7) << 4))) = v;
    }
  }

  const int po = w * 4;
  const int prow = lane >> 3;
  const int pcol = (lane & 7) * 8;

  float rsum[4][4] = {};  // [mi][r]

  for (int nt = 0; nt < 16; ++nt) {
    f32x4 acc[4][4] = {};
    for (int kt = 0; kt < 256; kt += 64) {
      __syncthreads();
      #pragma unroll
      for (int p = 0; p < 4; ++p) {
        const int q = po + p;
        const int row = q * 8 + prow;
        gload16(Wc1T + (long)(nt * 128 + row) * 256 + kt + pcol, Bs + q * 512);
      }
      __syncthreads();
      #pragma unroll
      for (int ks = 0; ks < 2; ++ks) {
        bf16x8 af[4], bfr[4];
        #pragma unroll
        for (int mi = 0; mi < 4; ++mi) {
          const int row = wr * 64 + mi * 16 + (lane & 15);
          const int ce = kt + ks * 32 + (lane >> 4) * 8;
          af[mi] = *(const bf16x8*)((const char*)Ae + row * 512 + ((ce * 2) ^ ((row & 7) << 4)));
        }
        #pragma unroll
        for (int ni = 0; ni < 4; ++ni) {
          const int row = wc * 64 + ni * 16 + (lane & 15);
          bfr[ni] = *(const bf16x8*)((const char*)Bs + row * 128 + ks * 64 + (lane >> 4) * 16);
        }
        #pragma unroll
        for (int mi = 0; mi < 4; ++mi)
          #pragma unroll
          for (int ni = 0; ni < 4; ++ni)
            acc[mi][ni] = __builtin_amdgcn_mfma_f32_16x16x32_bf16(af[mi], bfr[ni], acc[mi][ni], 0, 0, 0);
      }
    }
    #pragma unroll
    for (int mi = 0; mi < 4; ++mi) {
      #pragma unroll
      for (int ni = 0; ni < 4; ++ni) {
        const int col = nt * 128 + wc * 64 + ni * 16 + (lane & 15);
        const float bv = bc1[col], wv = Wc2[col];
        #pragma unroll
        for (int r = 0; r < 4; ++r)
          rsum[mi][r] += fmaxf(acc[mi][ni][r] + bv, 0.f) * wv;
      }
    }
  }

  // reduce over 16 col-lanes
  #pragma unroll
  for (int off = 1; off < 16; off <<= 1)
    #pragma unroll
    for (int mi = 0; mi < 4; ++mi)
      #pragma unroll
      for (int r = 0; r < 4; ++r)
        rsum[mi][r] += __shfl_xor(rsum[mi][r], off, 64);
  if ((lane & 15) == 0) {
    #pragma unroll
    for (int mi = 0; mi < 4; ++mi)
      #pragma unroll
      for (int r = 0; r < 4; ++r)
        red[wc][wr * 64 + mi * 16 + (lane >> 4) * 4 + r] = rsum[mi][r];
  }
  __syncthreads();
  if (t < 128)
    out[(long)(m0 + t) * 64 + 56 + k] = red[0][t] + red[1][t] + bc2[0];
}

// ---------------- pairwise reduce: on[p,b] ----------------
__global__ __launch_bounds__(256)
void pair_reduce_kernel(const unsigned short* __restrict__ UVT,  // [8][Mc][4096]
                        const float* __restrict__ bon1, const float* __restrict__ Won2,
                        const float* __restrict__ bon2,
                        float* __restrict__ out, int Mc) {
  __shared__ unsigned short uv[8 * 4096];
  const int b = blockIdx.x, t = threadIdx.x;
  const long kstride = (long)Mc * 4096;
  const unsigned short* src = UVT + (long)b * 4096;
  for (int k = 0; k < 8; ++k) {
    const unsigned short* s = src + (long)k * kstride;
    #pragma unroll
    for (int c0 = 0; c0 < 2; ++c0) {
      int c = c0 * 256 + t;
      int byte = k * 8192 + ((c * 16) ^ ((k & 7) << 4));
      *(float4*)((char*)uv + byte) = *(const float4*)(s + c * 8);
    }
  }
  __syncthreads();
  const int p = t & 63, q = t >> 6;
  float acc = 0.f;
  if (p < 56) {
    const int i = p / 7;
    const int jj = p % 7;
    const int j = jj + (jj >= i);
    const char* ubase = (const char*)uv + i * 8192;
    const char* vbase = (const char*)uv + j * 8192;
    const int uswz = (i & 7) << 4, vswz = (j & 7) << 4;
    for (int it = 0; it < 64; ++it) {
      const int h = q * 512 + it * 8;
      bf16x8 uu = *(const bf16x8*)(ubase + ((h * 2) ^ uswz));
      bf16x8 vv = *(const bf16x8*)(vbase + ((4096 + h * 2) ^ vswz));
      float4 ba = *(const float4*)(bon1 + h);
      float4 bb = *(const float4*)(bon1 + h + 4);
      float4 wa = *(const float4*)(Won2 + h);
      float4 wb = *(const float4*)(Won2 + h + 4);
      float bs[8] = {ba.x, ba.y, ba.z, ba.w, bb.x, bb.y, bb.z, bb.w};
      float wv[8] = {wa.x, wa.y, wa.z, wa.w, wb.x, wb.y, wb.z, wb.w};
      #pragma unroll
      for (int e = 0; e < 8; ++e) {
        float x = bf2f(uu[e]) + bf2f(vv[e]) + bs[e];
        acc += fmaxf(x, 0.f) * wv[e];
      }
    }
  }
  __syncthreads();
  float* red = (float*)uv;
  red[q * 64 + p] = acc;
  __syncthreads();
  if (t < 56)
    out[(long)b * 64 + t] = red[t] + red[64 + t] + red[128 + t] + red[192 + t] + bon2[0];
}

extern "C" void kernel_launch(void* const* d_in, const int* in_sizes, int n_in,
                              void* d_out, int out_size, void* d_ws, size_t ws_size,
                              hipStream_t stream) {
  (void)in_sizes; (void)n_in; (void)out_size;
  const float* input = (const float*)d_in[0];
  const float* W1    = (const float*)d_in[1];
  const float* b1    = (const float*)d_in[2];
  const float* W2    = (const float*)d_in[3];
  const float* b2    = (const float*)d_in[4];
  const float* Won1  = (const float*)d_in[5];
  const float* bon1  = (const float*)d_in[6];
  const float* Won2  = (const float*)d_in[7];
  const float* bon2  = (const float*)d_in[8];
  const float* Wc1   = (const float*)d_in[9];
  const float* bc1   = (const float*)d_in[10];
  const float* Wc2   = (const float*)d_in[11];
  const float* bc2   = (const float*)d_in[12];
  float* out = (float*)d_out;

  char* base = (char*)d_ws;
  unsigned short* inputb = (unsigned short*)(base);                  //  8 MB
  unsigned short* W1T    = (unsigned short*)(base + 8388608L);       // 32 MB
  unsigned short* W2T    = (unsigned short*)(base + 41943040L);      //  8 MB
  unsigned short* WcatT  = (unsigned short*)(base + 50331648L);      //  2 MB  [4096,256]
  unsigned short* Wc1T   = (unsigned short*)(base + 52428800L);      //  1 MB  [2048,256]
  char* chunkbase = base + 53477376L;

  // fewest chunks that fit: per-chunk bytes = Mc * (32768 + 4096 + 65536)
  int nc = 32;
  const int opts[6] = {1, 2, 4, 8, 16, 32};
  for (int oi = 0; oi < 6; ++oi) {
    long Mc_ = 4096 / opts[oi];
    if (53477376L + Mc_ * 102400L <= (long)ws_size) { nc = opts[oi]; break; }
  }
  const int Mc = 4096 / nc;
  unsigned short* hbuf   = (unsigned short*)chunkbase;
  unsigned short* embbuf = (unsigned short*)(chunkbase + (long)Mc * 32768L);
  unsigned short* UVTbuf = (unsigned short*)(chunkbase + (long)Mc * 36864L);

  dim3 tb(32, 8);
  cvt_f32_bf16<<<dim3(2048), 256, 0, stream>>>(input, inputb, (long)4096 * 1024);
  transpose_f32_bf16<<<dim3(64, 32, 8), tb, 0, stream>>>(W1, W1T, 1024, 2048,
                                                         (long)1024 * 2048, (long)2048 * 1024);
  transpose_f32_bf16<<<dim3(8, 64, 8), tb, 0, stream>>>(W2, W2T, 2048, 256,
                                                        (long)2048 * 256, (long)256 * 2048);
  transpose_f32_bf16<<<dim3(64, 8, 1), tb, 0, stream>>>(Won1, WcatT, 256, 2048, 0, 0);
  transpose_f32_bf16<<<dim3(64, 8, 1), tb, 0, stream>>>(Won1 + 256 * 2048,
                                                        WcatT + (long)2048 * 256, 256, 2048, 0, 0);
  transpose_f32_bf16<<<dim3(64, 8, 1), tb, 0, stream>>>(Wc1, Wc1T, 256, 2048, 0, 0);

  for (int cc = 0; cc < nc; ++cc) {
    const long b0 = (long)cc * Mc;
    const int nyc = Mc / 128;
    // h[k] = relu(input @ W1[k] + b1[k])   [Mc,2048]
    gemm_bf16<true, true><<<dim3(16 * nyc * 8), 256, 0, stream>>>(
        inputb + b0 * 1024, W1T, b1, hbuf, 2048, 1024, 16, nyc,
        0L, (long)2048 * 1024, 2048L, (long)Mc * 2048);
    // emb[k] = h[k] @ W2[k] + b2[k]        [Mc,256]
    gemm_bf16<true, false><<<dim3(2 * nyc * 8), 256, 0, stream>>>(
        hbuf, W2T, b2, embbuf, 256, 2048, 2, nyc,
        (long)Mc * 2048, (long)256 * 2048, 256L, (long)Mc * 256);
    // UVT[k] = emb[k] @ [Won1_top | Won1_bot]   [Mc,4096]
    gemm_bf16<false, false><<<dim3(32 * nyc * 8), 256, 0, stream>>>(
        embbuf, WcatT, nullptr, UVTbuf, 4096, 256, 32, nyc,
        (long)Mc * 256, 0L, 0L, (long)Mc * 4096);
    // on[p,b]
    pair_reduce_kernel<<<dim3(Mc), 256, 0, stream>>>(UVTbuf, bon1, Won2, bon2, out + b0 * 64, Mc);
    // clear[k,b] fused
    clear_fused<<<dim3(nyc, 8), 256, 0, stream>>>(embbuf, Wc1T, bc1, Wc2, bc2, out + b0 * 64, Mc);
  }
}